// Round 2
// baseline (2264.646 us; speedup 1.0000x reference)
//
#include <hip/hip_runtime.h>
#include <hip/hip_bf16.h>

#define T_DIM 512
#define H_DIM 4096
#define F_DIM 14336
#define KSEG  8   // split-K segments for down GEMM (14336/8 = 1792 = 28 x 64)

typedef __attribute__((ext_vector_type(8))) short bf16x8;
typedef __attribute__((ext_vector_type(4))) float f32x4;

__device__ __forceinline__ unsigned short f2bf(float f) {
    union { float f; unsigned u; } v; v.f = f;
    unsigned r = v.u + 0x7fffu + ((v.u >> 16) & 1u);  // RNE
    return (unsigned short)(r >> 16);
}

// Zero d_out (harness poisons with 0xAA; down_kernel accumulates via atomics).
__global__ __launch_bounds__(256) void zero_out(float4* __restrict__ out) {
    out[blockIdx.x * 256 + threadIdx.x] = make_float4(0.f, 0.f, 0.f, 0.f);
}

// X fp32 -> bf16 once.
__global__ __launch_bounds__(256) void cvt_x(const float* __restrict__ X,
                                             unsigned short* __restrict__ Xb) {
    int i = (blockIdx.x * 256 + threadIdx.x) * 4;
    float4 v = *(const float4*)&X[i];
    ushort4 o;
    o.x = f2bf(v.x); o.y = f2bf(v.y); o.z = f2bf(v.z); o.w = f2bf(v.w);
    *(ushort4*)&Xb[i] = o;
}

// ---------------------------------------------------------------------------
// G = silu(X@W1^T) * (X@W3^T) -> bf16 [T,F]
// Tile M128 x N64 x K64(=GROUP). 4 waves: wave&1 = m-half, wave>>1 = matrix.
// ONLY the weight streams (HBM-latency) are register-prefetched: 8 int4 =
// 32 VGPRs live across the barrier. X and scales are L2/L3-resident and
// loaded synchronously.
// Occupancy: 4 blocks/CU (VGPR 108 <= 128, LDS 36.9KB x4 = 147KB <= 160KB).
// Previous (256,2) left the kernel latency-bound at 18% occupancy / 19% HBM.
// Grid: flat 896, XCD-swizzled (4 m-siblings concurrent per XCD), fully
// co-resident at 4/CU (no scheduling tail).
// ---------------------------------------------------------------------------
__global__ __launch_bounds__(256, 4)
void gate_up_kernel(const unsigned short* __restrict__ Xb,
                    const int* __restrict__ W1q, const float* __restrict__ sc1,
                    const float* __restrict__ zp1,
                    const int* __restrict__ W3q, const float* __restrict__ sc3,
                    const float* __restrict__ zp3,
                    unsigned short* __restrict__ G)
{
    constexpr int LK = 72;  // 144 B row stride, 16B-aligned, +4 bank shift/row
    __shared__ __align__(16) char smem[(128 + 64 + 64) * LK * 2];  // 36864 B
    unsigned short* sX  = (unsigned short*)smem;
    unsigned short* sW1 = (unsigned short*)(smem + 128 * LK * 2);
    unsigned short* sW3 = (unsigned short*)(smem + 192 * LK * 2);
    float* sEx = (float*)smem;  // epilogue reuse: 128*65*4 = 33280 B

    const int t = threadIdx.x, wave = t >> 6, lane = t & 63;
    const int r = lane & 15, q = lane >> 4;
    const int mh  = (wave & 1) * 64;   // wave's m-offset in tile
    const int mat = wave >> 1;         // 0 -> W1, 1 -> W3

    const int b = blockIdx.x;
    const int xcd = b & 7, lb = b >> 3;         // lb in [0,112)
    const int m0 = (lb & 3) * 128;
    const int n0 = (xcd * 28 + (lb >> 2)) * 64; // n-tile in [0,224)
    const int SG = H_DIM / 64;

    const int xrow = t >> 3, xch = (t & 7) * 8;   // X: rows xrow+32i, 16B chunk
    const int wrow = t >> 4, wc = (t & 15) * 4;   // W: rows wrow+16i, 4 int32

    // weight-only prefetch (32 VGPRs live across barriers)
    int4 pW1[4], pW3[4];
    #pragma unroll
    for (int i = 0; i < 4; ++i) {
        size_t off = (size_t)(n0 + wrow + 16 * i) * H_DIM + wc;
        pW1[i] = *(const int4*)&W1q[off];
        pW3[i] = *(const int4*)&W3q[off];
    }

    f32x4 acc[4][4];
    #pragma unroll
    for (int a = 0; a < 4; ++a)
        #pragma unroll
        for (int c = 0; c < 4; ++c) acc[a][c] = (f32x4){0.f, 0.f, 0.f, 0.f};

    for (int k0 = 0; k0 < H_DIM; k0 += 64) {
        const int gidx = k0 >> 6;

        // ---- X tile: sync copy (L2/L3-resident, 4 MB total) ----
        #pragma unroll
        for (int i = 0; i < 4; ++i) {
            int4 xv = *(const int4*)&Xb[(size_t)(m0 + xrow + 32 * i) * H_DIM + k0 + xch];
            *(int4*)&sX[(xrow + 32 * i) * LK + xch] = xv;
        }
        // ---- dequant prefetched weights -> LDS (scales loaded sync, L2) ----
        #pragma unroll
        for (int i = 0; i < 4; ++i) {
            int row = wrow + 16 * i;
            int sidx = (n0 + row) * SG + gidx;
            float s = sc1[sidx], nzs = -zp1[sidx] * s;
            int4 qv = pW1[i];
            ushort4 o;
            o.x = f2bf(fmaf((float)qv.x, s, nzs)); o.y = f2bf(fmaf((float)qv.y, s, nzs));
            o.z = f2bf(fmaf((float)qv.z, s, nzs)); o.w = f2bf(fmaf((float)qv.w, s, nzs));
            *(ushort4*)&sW1[row * LK + wc] = o;
            s = sc3[sidx]; nzs = -zp3[sidx] * s;
            qv = pW3[i];
            o.x = f2bf(fmaf((float)qv.x, s, nzs)); o.y = f2bf(fmaf((float)qv.y, s, nzs));
            o.z = f2bf(fmaf((float)qv.z, s, nzs)); o.w = f2bf(fmaf((float)qv.w, s, nzs));
            *(ushort4*)&sW3[row * LK + wc] = o;
        }
        // ---- issue next K-tile's weight loads (stay in flight over MFMA) ----
        int kn = k0 + 64;
        if (kn < H_DIM) {
            #pragma unroll
            for (int i = 0; i < 4; ++i) {
                size_t off = (size_t)(n0 + wrow + 16 * i) * H_DIM + kn + wc;
                pW1[i] = *(const int4*)&W1q[off];
                pW3[i] = *(const int4*)&W3q[off];
            }
        }
        __syncthreads();

        const unsigned short* sB = mat ? sW3 : sW1;
        #pragma unroll
        for (int kh = 0; kh < 2; ++kh) {
            const int kb = kh * 32 + q * 8;
            bf16x8 av[4], bv[4];
            #pragma unroll
            for (int im = 0; im < 4; ++im)
                av[im] = *(const bf16x8*)&sX[(mh + im * 16 + r) * LK + kb];
            #pragma unroll
            for (int j = 0; j < 4; ++j)
                bv[j] = *(const bf16x8*)&sB[(j * 16 + r) * LK + kb];
            #pragma unroll
            for (int im = 0; im < 4; ++im)
                #pragma unroll
                for (int j = 0; j < 4; ++j)
                    acc[im][j] = __builtin_amdgcn_mfma_f32_16x16x32_bf16(av[im], bv[j], acc[im][j], 0, 0, 0);
        }
        __syncthreads();
    }

    // ---- epilogue: exchange g3 via LDS, then silu(g1)*g3 ----
    if (mat == 1) {
        #pragma unroll
        for (int im = 0; im < 4; ++im)
            #pragma unroll
            for (int j = 0; j < 4; ++j)
                #pragma unroll
                for (int reg = 0; reg < 4; ++reg)
                    sEx[(mh + im * 16 + q * 4 + reg) * 65 + j * 16 + r] = acc[im][j][reg];
    }
    __syncthreads();
    if (mat == 0) {
        #pragma unroll
        for (int im = 0; im < 4; ++im)
            #pragma unroll
            for (int j = 0; j < 4; ++j)
                #pragma unroll
                for (int reg = 0; reg < 4; ++reg) {
                    int ml = mh + im * 16 + q * 4 + reg;
                    int nl = j * 16 + r;
                    float g1 = acc[im][j][reg];
                    float g3 = sEx[ml * 65 + nl];
                    float val = g1 / (1.f + __expf(-g1)) * g3;
                    G[(size_t)(m0 + ml) * F_DIM + n0 + nl] = f2bf(val);
                }
    }
}

// ---------------------------------------------------------------------------
// out += G @ W2^T (split-K, fp32 atomics). Tile M128 x N128 x K64, 4 waves
// x 64x64. Weight-only register prefetch; G + scales loaded sync (L2/L3).
// Occupancy: 4 blocks/CU (same arithmetic as gate_up).
// Grid: flat 1024 = 4(m) x 32(n) x 8(kseg), XCD-swizzled, exactly 4/CU.
// ---------------------------------------------------------------------------
__global__ __launch_bounds__(256, 4)
void down_kernel(const unsigned short* __restrict__ G,
                 const int* __restrict__ W2q, const float* __restrict__ sc2,
                 const float* __restrict__ zp2,
                 float* __restrict__ Out)
{
    constexpr int LK = 72;
    __shared__ __align__(16) char smem[(128 + 128) * LK * 2];  // 36864 B
    unsigned short* sA = (unsigned short*)smem;
    unsigned short* sW = (unsigned short*)(smem + 128 * LK * 2);

    const int t = threadIdx.x, wave = t >> 6, lane = t & 63;
    const int r = lane & 15, q = lane >> 4;
    const int wm = (wave & 1) * 64, wn = (wave >> 1) * 64;

    const int b = blockIdx.x;
    const int xcd = b & 7, lb = b >> 3;          // lb in [0,128)
    const int m0 = (lb & 3) * 128;
    const int pair = xcd * 32 + (lb >> 2);       // [0,256)
    const int n0 = (pair >> 3) * 128;            // 32 n-tiles
    const int kbeg = (pair & 7) * (F_DIM / KSEG);
    const int kend = kbeg + (F_DIM / KSEG);
    const int SG = F_DIM / 64;

    const int arow = t >> 3, ach = (t & 7) * 8;
    const int wrow = t >> 4, wc = (t & 15) * 4;

    // weight-only prefetch (32 VGPRs)
    int4 pW[8];
    #pragma unroll
    for (int i = 0; i < 8; ++i)
        pW[i] = *(const int4*)&W2q[(size_t)(n0 + wrow + 16 * i) * F_DIM + kbeg + wc];

    f32x4 acc[4][4];
    #pragma unroll
    for (int a = 0; a < 4; ++a)
        #pragma unroll
        for (int c = 0; c < 4; ++c) acc[a][c] = (f32x4){0.f, 0.f, 0.f, 0.f};

    for (int k0 = kbeg; k0 < kend; k0 += 64) {
        const int gidx = k0 >> 6;

        // ---- A tile (G bf16): sync copy (L3-resident, 14.7 MB) ----
        #pragma unroll
        for (int i = 0; i < 4; ++i) {
            int4 gv = *(const int4*)&G[(size_t)(m0 + arow + 32 * i) * F_DIM + k0 + ach];
            *(int4*)&sA[(arow + 32 * i) * LK + ach] = gv;
        }
        // ---- dequant prefetched W2 -> LDS ----
        #pragma unroll
        for (int i = 0; i < 8; ++i) {
            int row = wrow + 16 * i;
            int sidx = (n0 + row) * SG + gidx;
            float s = sc2[sidx], nzs = -zp2[sidx] * s;
            int4 qv = pW[i];
            ushort4 o;
            o.x = f2bf(fmaf((float)qv.x, s, nzs)); o.y = f2bf(fmaf((float)qv.y, s, nzs));
            o.z = f2bf(fmaf((float)qv.z, s, nzs)); o.w = f2bf(fmaf((float)qv.w, s, nzs));
            *(ushort4*)&sW[row * LK + wc] = o;
        }
        // ---- issue next K-tile weight loads ----
        int kn = k0 + 64;
        if (kn < kend) {
            #pragma unroll
            for (int i = 0; i < 8; ++i)
                pW[i] = *(const int4*)&W2q[(size_t)(n0 + wrow + 16 * i) * F_DIM + kn + wc];
        }
        __syncthreads();

        #pragma unroll
        for (int kh = 0; kh < 2; ++kh) {
            const int kb = kh * 32 + q * 8;
            bf16x8 av[4], bv[4];
            #pragma unroll
            for (int im = 0; im < 4; ++im)
                av[im] = *(const bf16x8*)&sA[(wm + im * 16 + r) * LK + kb];
            #pragma unroll
            for (int j = 0; j < 4; ++j)
                bv[j] = *(const bf16x8*)&sW[(wn + j * 16 + r) * LK + kb];
            #pragma unroll
            for (int im = 0; im < 4; ++im)
                #pragma unroll
                for (int j = 0; j < 4; ++j)
                    acc[im][j] = __builtin_amdgcn_mfma_f32_16x16x32_bf16(av[im], bv[j], acc[im][j], 0, 0, 0);
        }
        __syncthreads();
    }

    #pragma unroll
    for (int im = 0; im < 4; ++im)
        #pragma unroll
        for (int j = 0; j < 4; ++j)
            #pragma unroll
            for (int reg = 0; reg < 4; ++reg) {
                int m = m0 + wm + im * 16 + q * 4 + reg;
                int h = n0 + wn + j * 16 + r;
                atomicAdd(&Out[(size_t)m * H_DIM + h], acc[im][j][reg]);
            }
}

extern "C" void kernel_launch(void* const* d_in, const int* in_sizes, int n_in,
                              void* d_out, int out_size, void* d_ws, size_t ws_size,
                              hipStream_t stream) {
    const float* X   = (const float*)d_in[0];
    const int*   W1q = (const int*)d_in[1];
    const float* s1  = (const float*)d_in[2];
    const float* z1  = (const float*)d_in[3];
    const int*   W3q = (const int*)d_in[4];
    const float* s3  = (const float*)d_in[5];
    const float* z3  = (const float*)d_in[6];
    const int*   W2q = (const int*)d_in[7];
    const float* s2  = (const float*)d_in[8];
    const float* z2  = (const float*)d_in[9];
    float* Out = (float*)d_out;

    unsigned short* Xb = (unsigned short*)d_ws;                       // 4 MB
    unsigned short* G  = (unsigned short*)((char*)d_ws + (4 << 20));  // 14.7 MB

    zero_out<<<2048, 256, 0, stream>>>((float4*)Out);
    cvt_x<<<2048, 256, 0, stream>>>(X, Xb);
    gate_up_kernel<<<896, 256, 0, stream>>>(Xb, W1q, s1, z1, W3q, s3, z3, G);
    down_kernel<<<1024, 256, 0, stream>>>(G, W2q, s2, z2, Out);
}

// Round 3
// 1294.328 us; speedup vs baseline: 1.7497x; 1.7497x over previous
//
#include <hip/hip_runtime.h>
#include <hip/hip_bf16.h>

#define T_DIM 512
#define H_DIM 4096
#define F_DIM 14336
#define KSEG  8   // split-K segments for down GEMM (14336/8 = 1792 = 28 x 64)

typedef __attribute__((ext_vector_type(8))) short bf16x8;
typedef __attribute__((ext_vector_type(4))) float f32x4;

__device__ __forceinline__ unsigned short f2bf(float f) {
    union { float f; unsigned u; } v; v.f = f;
    unsigned r = v.u + 0x7fffu + ((v.u >> 16) & 1u);  // RNE
    return (unsigned short)(r >> 16);
}

// Zero d_out (harness poisons with 0xAA; down_kernel accumulates via atomics).
__global__ __launch_bounds__(256) void zero_out(float4* __restrict__ out) {
    out[blockIdx.x * 256 + threadIdx.x] = make_float4(0.f, 0.f, 0.f, 0.f);
}

// X fp32 -> bf16 once.
__global__ __launch_bounds__(256) void cvt_x(const float* __restrict__ X,
                                             unsigned short* __restrict__ Xb) {
    int i = (blockIdx.x * 256 + threadIdx.x) * 4;
    float4 v = *(const float4*)&X[i];
    ushort4 o;
    o.x = f2bf(v.x); o.y = f2bf(v.y); o.z = f2bf(v.z); o.w = f2bf(v.w);
    *(ushort4*)&Xb[i] = o;
}

// ---------------------------------------------------------------------------
// G = silu(X@W1^T) * (X@W3^T) -> bf16 [T,F]
// Tile M128 x N64 x K64(=GROUP). 4 waves: wave&1 = m-half, wave>>1 = matrix.
// ONLY the weight streams (HBM-latency) are register-prefetched: 8 int4 =
// 32 VGPRs live across the barrier. X and scales are L2/L3-resident and
// loaded synchronously.
// Occupancy: __launch_bounds__(256,3) -> VGPR cap ~170, natural alloc 108
// fits with slack (NO spill), 3 blocks/CU guaranteed (LDS 36.9K x3 = 111K).
// History: (256,2) = 18% occ, latency-bound, 347us. (256,4) = compiler cut
// VGPR to 64, acc[4][4] spilled, 3 GB scratch traffic, 1376us. (256,3) is
// the max occupancy that provably cannot spill the 64-reg accumulator.
// Grid: flat 896, XCD-swizzled (4 m-siblings concurrent per XCD).
// ---------------------------------------------------------------------------
__global__ __launch_bounds__(256, 3)
void gate_up_kernel(const unsigned short* __restrict__ Xb,
                    const int* __restrict__ W1q, const float* __restrict__ sc1,
                    const float* __restrict__ zp1,
                    const int* __restrict__ W3q, const float* __restrict__ sc3,
                    const float* __restrict__ zp3,
                    unsigned short* __restrict__ G)
{
    constexpr int LK = 72;  // 144 B row stride, 16B-aligned, +4 bank shift/row
    __shared__ __align__(16) char smem[(128 + 64 + 64) * LK * 2];  // 36864 B
    unsigned short* sX  = (unsigned short*)smem;
    unsigned short* sW1 = (unsigned short*)(smem + 128 * LK * 2);
    unsigned short* sW3 = (unsigned short*)(smem + 192 * LK * 2);
    float* sEx = (float*)smem;  // epilogue reuse: 128*65*4 = 33280 B

    const int t = threadIdx.x, wave = t >> 6, lane = t & 63;
    const int r = lane & 15, q = lane >> 4;
    const int mh  = (wave & 1) * 64;   // wave's m-offset in tile
    const int mat = wave >> 1;         // 0 -> W1, 1 -> W3

    const int b = blockIdx.x;
    const int xcd = b & 7, lb = b >> 3;         // lb in [0,112)
    const int m0 = (lb & 3) * 128;
    const int n0 = (xcd * 28 + (lb >> 2)) * 64; // n-tile in [0,224)
    const int SG = H_DIM / 64;

    const int xrow = t >> 3, xch = (t & 7) * 8;   // X: rows xrow+32i, 16B chunk
    const int wrow = t >> 4, wc = (t & 15) * 4;   // W: rows wrow+16i, 4 int32

    // weight-only prefetch (32 VGPRs live across barriers)
    int4 pW1[4], pW3[4];
    #pragma unroll
    for (int i = 0; i < 4; ++i) {
        size_t off = (size_t)(n0 + wrow + 16 * i) * H_DIM + wc;
        pW1[i] = *(const int4*)&W1q[off];
        pW3[i] = *(const int4*)&W3q[off];
    }

    f32x4 acc[4][4];
    #pragma unroll
    for (int a = 0; a < 4; ++a)
        #pragma unroll
        for (int c = 0; c < 4; ++c) acc[a][c] = (f32x4){0.f, 0.f, 0.f, 0.f};

    for (int k0 = 0; k0 < H_DIM; k0 += 64) {
        const int gidx = k0 >> 6;

        // ---- X tile: sync copy (L2/L3-resident, 4 MB total) ----
        #pragma unroll
        for (int i = 0; i < 4; ++i) {
            int4 xv = *(const int4*)&Xb[(size_t)(m0 + xrow + 32 * i) * H_DIM + k0 + xch];
            *(int4*)&sX[(xrow + 32 * i) * LK + xch] = xv;
        }
        // ---- dequant prefetched weights -> LDS (scales loaded sync, L2) ----
        #pragma unroll
        for (int i = 0; i < 4; ++i) {
            int row = wrow + 16 * i;
            int sidx = (n0 + row) * SG + gidx;
            float s = sc1[sidx], nzs = -zp1[sidx] * s;
            int4 qv = pW1[i];
            ushort4 o;
            o.x = f2bf(fmaf((float)qv.x, s, nzs)); o.y = f2bf(fmaf((float)qv.y, s, nzs));
            o.z = f2bf(fmaf((float)qv.z, s, nzs)); o.w = f2bf(fmaf((float)qv.w, s, nzs));
            *(ushort4*)&sW1[row * LK + wc] = o;
            s = sc3[sidx]; nzs = -zp3[sidx] * s;
            qv = pW3[i];
            o.x = f2bf(fmaf((float)qv.x, s, nzs)); o.y = f2bf(fmaf((float)qv.y, s, nzs));
            o.z = f2bf(fmaf((float)qv.z, s, nzs)); o.w = f2bf(fmaf((float)qv.w, s, nzs));
            *(ushort4*)&sW3[row * LK + wc] = o;
        }
        // ---- issue next K-tile's weight loads (stay in flight over MFMA) ----
        int kn = k0 + 64;
        if (kn < H_DIM) {
            #pragma unroll
            for (int i = 0; i < 4; ++i) {
                size_t off = (size_t)(n0 + wrow + 16 * i) * H_DIM + kn + wc;
                pW1[i] = *(const int4*)&W1q[off];
                pW3[i] = *(const int4*)&W3q[off];
            }
        }
        __syncthreads();

        const unsigned short* sB = mat ? sW3 : sW1;
        #pragma unroll
        for (int kh = 0; kh < 2; ++kh) {
            const int kb = kh * 32 + q * 8;
            bf16x8 av[4], bv[4];
            #pragma unroll
            for (int im = 0; im < 4; ++im)
                av[im] = *(const bf16x8*)&sX[(mh + im * 16 + r) * LK + kb];
            #pragma unroll
            for (int j = 0; j < 4; ++j)
                bv[j] = *(const bf16x8*)&sB[(j * 16 + r) * LK + kb];
            #pragma unroll
            for (int im = 0; im < 4; ++im)
                #pragma unroll
                for (int j = 0; j < 4; ++j)
                    acc[im][j] = __builtin_amdgcn_mfma_f32_16x16x32_bf16(av[im], bv[j], acc[im][j], 0, 0, 0);
        }
        __syncthreads();
    }

    // ---- epilogue: exchange g3 via LDS, then silu(g1)*g3 ----
    if (mat == 1) {
        #pragma unroll
        for (int im = 0; im < 4; ++im)
            #pragma unroll
            for (int j = 0; j < 4; ++j)
                #pragma unroll
                for (int reg = 0; reg < 4; ++reg)
                    sEx[(mh + im * 16 + q * 4 + reg) * 65 + j * 16 + r] = acc[im][j][reg];
    }
    __syncthreads();
    if (mat == 0) {
        #pragma unroll
        for (int im = 0; im < 4; ++im)
            #pragma unroll
            for (int j = 0; j < 4; ++j)
                #pragma unroll
                for (int reg = 0; reg < 4; ++reg) {
                    int ml = mh + im * 16 + q * 4 + reg;
                    int nl = j * 16 + r;
                    float g1 = acc[im][j][reg];
                    float g3 = sEx[ml * 65 + nl];
                    float val = g1 / (1.f + __expf(-g1)) * g3;
                    G[(size_t)(m0 + ml) * F_DIM + n0 + nl] = f2bf(val);
                }
    }
}

// ---------------------------------------------------------------------------
// out += G @ W2^T (split-K, fp32 atomics). Tile M128 x N128 x K64, 4 waves
// x 64x64. Weight-only register prefetch; G + scales loaded sync (L2/L3).
// Occupancy: (256,3) — same no-spill arithmetic as gate_up.
// Grid: flat 1024 = 4(m) x 32(n) x 8(kseg), XCD-swizzled.
// ---------------------------------------------------------------------------
__global__ __launch_bounds__(256, 3)
void down_kernel(const unsigned short* __restrict__ G,
                 const int* __restrict__ W2q, const float* __restrict__ sc2,
                 const float* __restrict__ zp2,
                 float* __restrict__ Out)
{
    constexpr int LK = 72;
    __shared__ __align__(16) char smem[(128 + 128) * LK * 2];  // 36864 B
    unsigned short* sA = (unsigned short*)smem;
    unsigned short* sW = (unsigned short*)(smem + 128 * LK * 2);

    const int t = threadIdx.x, wave = t >> 6, lane = t & 63;
    const int r = lane & 15, q = lane >> 4;
    const int wm = (wave & 1) * 64, wn = (wave >> 1) * 64;

    const int b = blockIdx.x;
    const int xcd = b & 7, lb = b >> 3;          // lb in [0,128)
    const int m0 = (lb & 3) * 128;
    const int pair = xcd * 32 + (lb >> 2);       // [0,256)
    const int n0 = (pair >> 3) * 128;            // 32 n-tiles
    const int kbeg = (pair & 7) * (F_DIM / KSEG);
    const int kend = kbeg + (F_DIM / KSEG);
    const int SG = F_DIM / 64;

    const int arow = t >> 3, ach = (t & 7) * 8;
    const int wrow = t >> 4, wc = (t & 15) * 4;

    // weight-only prefetch (32 VGPRs)
    int4 pW[8];
    #pragma unroll
    for (int i = 0; i < 8; ++i)
        pW[i] = *(const int4*)&W2q[(size_t)(n0 + wrow + 16 * i) * F_DIM + kbeg + wc];

    f32x4 acc[4][4];
    #pragma unroll
    for (int a = 0; a < 4; ++a)
        #pragma unroll
        for (int c = 0; c < 4; ++c) acc[a][c] = (f32x4){0.f, 0.f, 0.f, 0.f};

    for (int k0 = kbeg; k0 < kend; k0 += 64) {
        const int gidx = k0 >> 6;

        // ---- A tile (G bf16): sync copy (L3-resident, 14.7 MB) ----
        #pragma unroll
        for (int i = 0; i < 4; ++i) {
            int4 gv = *(const int4*)&G[(size_t)(m0 + arow + 32 * i) * F_DIM + k0 + ach];
            *(int4*)&sA[(arow + 32 * i) * LK + ach] = gv;
        }
        // ---- dequant prefetched W2 -> LDS ----
        #pragma unroll
        for (int i = 0; i < 8; ++i) {
            int row = wrow + 16 * i;
            int sidx = (n0 + row) * SG + gidx;
            float s = sc2[sidx], nzs = -zp2[sidx] * s;
            int4 qv = pW[i];
            ushort4 o;
            o.x = f2bf(fmaf((float)qv.x, s, nzs)); o.y = f2bf(fmaf((float)qv.y, s, nzs));
            o.z = f2bf(fmaf((float)qv.z, s, nzs)); o.w = f2bf(fmaf((float)qv.w, s, nzs));
            *(ushort4*)&sW[row * LK + wc] = o;
        }
        // ---- issue next K-tile weight loads ----
        int kn = k0 + 64;
        if (kn < kend) {
            #pragma unroll
            for (int i = 0; i < 8; ++i)
                pW[i] = *(const int4*)&W2q[(size_t)(n0 + wrow + 16 * i) * F_DIM + kn + wc];
        }
        __syncthreads();

        #pragma unroll
        for (int kh = 0; kh < 2; ++kh) {
            const int kb = kh * 32 + q * 8;
            bf16x8 av[4], bv[4];
            #pragma unroll
            for (int im = 0; im < 4; ++im)
                av[im] = *(const bf16x8*)&sA[(wm + im * 16 + r) * LK + kb];
            #pragma unroll
            for (int j = 0; j < 4; ++j)
                bv[j] = *(const bf16x8*)&sW[(wn + j * 16 + r) * LK + kb];
            #pragma unroll
            for (int im = 0; im < 4; ++im)
                #pragma unroll
                for (int j = 0; j < 4; ++j)
                    acc[im][j] = __builtin_amdgcn_mfma_f32_16x16x32_bf16(av[im], bv[j], acc[im][j], 0, 0, 0);
        }
        __syncthreads();
    }

    #pragma unroll
    for (int im = 0; im < 4; ++im)
        #pragma unroll
        for (int j = 0; j < 4; ++j)
            #pragma unroll
            for (int reg = 0; reg < 4; ++reg) {
                int m = m0 + wm + im * 16 + q * 4 + reg;
                int h = n0 + wn + j * 16 + r;
                atomicAdd(&Out[(size_t)m * H_DIM + h], acc[im][j][reg]);
            }
}

extern "C" void kernel_launch(void* const* d_in, const int* in_sizes, int n_in,
                              void* d_out, int out_size, void* d_ws, size_t ws_size,
                              hipStream_t stream) {
    const float* X   = (const float*)d_in[0];
    const int*   W1q = (const int*)d_in[1];
    const float* s1  = (const float*)d_in[2];
    const float* z1  = (const float*)d_in[3];
    const int*   W3q = (const int*)d_in[4];
    const float* s3  = (const float*)d_in[5];
    const float* z3  = (const float*)d_in[6];
    const int*   W2q = (const int*)d_in[7];
    const float* s2  = (const float*)d_in[8];
    const float* z2  = (const float*)d_in[9];
    float* Out = (float*)d_out;

    unsigned short* Xb = (unsigned short*)d_ws;                       // 4 MB
    unsigned short* G  = (unsigned short*)((char*)d_ws + (4 << 20));  // 14.7 MB

    zero_out<<<2048, 256, 0, stream>>>((float4*)Out);
    cvt_x<<<2048, 256, 0, stream>>>(X, Xb);
    gate_up_kernel<<<896, 256, 0, stream>>>(Xb, W1q, s1, z1, W3q, s3, z3, G);
    down_kernel<<<1024, 256, 0, stream>>>(G, W2q, s2, z2, Out);
}

// Round 5
// 1226.807 us; speedup vs baseline: 1.8460x; 1.0550x over previous
//
#include <hip/hip_runtime.h>
#include <hip/hip_bf16.h>

#define T_DIM 512
#define H_DIM 4096
#define F_DIM 14336
#define KSEG  8   // split-K segments for down GEMM (14336/8 = 1792 = 28 x 64)

typedef __attribute__((ext_vector_type(8))) short bf16x8;
typedef __attribute__((ext_vector_type(4))) float f32x4;

// 1-op f32->bf16 (v_cvt_pk_bf16_f32, RNE in HW). The old bit-trick RNE was
// ~4 VALU ops/element and dominated the dequant phase.
__device__ __forceinline__ unsigned short f2bf(float f) {
    union { __hip_bfloat16 h; unsigned short u; } cv;
    cv.h = __float2bfloat16(f);
    return cv.u;
}

// Zero d_out (harness poisons with 0xAA; down_kernel accumulates via atomics).
__global__ __launch_bounds__(256) void zero_out(float4* __restrict__ out) {
    out[blockIdx.x * 256 + threadIdx.x] = make_float4(0.f, 0.f, 0.f, 0.f);
}

// X fp32 -> bf16 once.
__global__ __launch_bounds__(256) void cvt_x(const float* __restrict__ X,
                                             unsigned short* __restrict__ Xb) {
    int i = (blockIdx.x * 256 + threadIdx.x) * 4;
    float4 v = *(const float4*)&X[i];
    ushort4 o;
    o.x = f2bf(v.x); o.y = f2bf(v.y); o.z = f2bf(v.z); o.w = f2bf(v.w);
    *(ushort4*)&Xb[i] = o;
}

// ---------------------------------------------------------------------------
// G = silu(X@W1^T) * (X@W3^T) -> bf16 [T,F]
// Tile M128 x N64 x K64(=GROUP). 4 waves: wave&1 = m-half, wave>>1 = matrix.
// FULLY depth-1 software-pipelined: X tile, weights, AND scales/zeros are all
// register-prefetched one K-step ahead (T14 async-STAGE). Loop body has no
// VMEM wait on the critical path: ds_write from regs -> dequant (VALU) ->
// issue next-step loads -> barrier -> MFMA.
// Register budget: acc 64 + pW 32 + pX 16 + scales 16 + frag staging 32 +
// addr ~25 = ~185 <= 256 @ (256,2). Occupancy history: (256,3)/(256,4)
// squeeze arch VGPRs below the 172-reg live set (unified VGPR+AGPR file) and
// spill into the K-loop -> 2-4x slower. DO NOT raise the min-waves bound.
// Grid: flat 896, XCD-swizzled (4 m-siblings concurrent per XCD share the
// weight panels in their XCD's L2: FETCH ~515MB = near-unique traffic).
// ---------------------------------------------------------------------------
__global__ __launch_bounds__(256, 2)
void gate_up_kernel(const unsigned short* __restrict__ Xb,
                    const int* __restrict__ W1q, const float* __restrict__ sc1,
                    const float* __restrict__ zp1,
                    const int* __restrict__ W3q, const float* __restrict__ sc3,
                    const float* __restrict__ zp3,
                    unsigned short* __restrict__ G)
{
    constexpr int LK = 72;  // 144 B row stride, 16B-aligned, +4 bank shift/row
    __shared__ __align__(16) char smem[(128 + 64 + 64) * LK * 2];  // 36864 B
    unsigned short* sX  = (unsigned short*)smem;
    unsigned short* sW1 = (unsigned short*)(smem + 128 * LK * 2);
    unsigned short* sW3 = (unsigned short*)(smem + 192 * LK * 2);
    float* sEx = (float*)smem;  // epilogue reuse: 128*65*4 = 33280 B

    const int t = threadIdx.x, wave = t >> 6, lane = t & 63;
    const int r = lane & 15, q = lane >> 4;
    const int mh  = (wave & 1) * 64;   // wave's m-offset in tile
    const int mat = wave >> 1;         // 0 -> W1, 1 -> W3

    const int b = blockIdx.x;
    const int xcd = b & 7, lb = b >> 3;         // lb in [0,112)
    const int m0 = (lb & 3) * 128;
    const int n0 = (xcd * 28 + (lb >> 2)) * 64; // n-tile in [0,224)
    const int SG = H_DIM / 64;

    const int xrow = t >> 3, xch = (t & 7) * 8;   // X: rows xrow+32i, 16B chunk
    const int wrow = t >> 4, wc = (t & 15) * 4;   // W: rows wrow+16i, 4 int32

    // ---- depth-1 pipeline registers: all streams prefetched ----
    int4  pX[4];
    int4  pW1[4], pW3[4];
    float pS1[4], pZ1[4], pS3[4], pZ3[4];

    #pragma unroll
    for (int i = 0; i < 4; ++i)
        pX[i] = *(const int4*)&Xb[(size_t)(m0 + xrow + 32 * i) * H_DIM + xch];
    #pragma unroll
    for (int i = 0; i < 4; ++i) {
        size_t off = (size_t)(n0 + wrow + 16 * i) * H_DIM + wc;
        pW1[i] = *(const int4*)&W1q[off];
        pW3[i] = *(const int4*)&W3q[off];
        int sidx = (n0 + wrow + 16 * i) * SG;
        pS1[i] = sc1[sidx]; pZ1[i] = zp1[sidx];
        pS3[i] = sc3[sidx]; pZ3[i] = zp3[sidx];
    }

    f32x4 acc[4][4];
    #pragma unroll
    for (int a = 0; a < 4; ++a)
        #pragma unroll
        for (int c = 0; c < 4; ++c) acc[a][c] = (f32x4){0.f, 0.f, 0.f, 0.f};

    for (int k0 = 0; k0 < H_DIM; k0 += 64) {
        // ---- stage X tile from prefetch regs (no VMEM wait: loaded last iter) ----
        #pragma unroll
        for (int i = 0; i < 4; ++i)
            *(int4*)&sX[(xrow + 32 * i) * LK + xch] = pX[i];
        // ---- dequant prefetched weights -> LDS (scales from regs) ----
        #pragma unroll
        for (int i = 0; i < 4; ++i) {
            int row = wrow + 16 * i;
            float s = pS1[i], nzs = -pZ1[i] * s;
            int4 qv = pW1[i];
            ushort4 o;
            o.x = f2bf(fmaf((float)qv.x, s, nzs)); o.y = f2bf(fmaf((float)qv.y, s, nzs));
            o.z = f2bf(fmaf((float)qv.z, s, nzs)); o.w = f2bf(fmaf((float)qv.w, s, nzs));
            *(ushort4*)&sW1[row * LK + wc] = o;
            s = pS3[i]; nzs = -pZ3[i] * s;
            qv = pW3[i];
            o.x = f2bf(fmaf((float)qv.x, s, nzs)); o.y = f2bf(fmaf((float)qv.y, s, nzs));
            o.z = f2bf(fmaf((float)qv.z, s, nzs)); o.w = f2bf(fmaf((float)qv.w, s, nzs));
            *(ushort4*)&sW3[row * LK + wc] = o;
        }
        // ---- issue ALL next-K-tile loads (in flight across MFMA phase) ----
        int kn = k0 + 64;
        if (kn < H_DIM) {
            int gn = kn >> 6;
            #pragma unroll
            for (int i = 0; i < 4; ++i)
                pX[i] = *(const int4*)&Xb[(size_t)(m0 + xrow + 32 * i) * H_DIM + kn + xch];
            #pragma unroll
            for (int i = 0; i < 4; ++i) {
                size_t off = (size_t)(n0 + wrow + 16 * i) * H_DIM + kn + wc;
                pW1[i] = *(const int4*)&W1q[off];
                pW3[i] = *(const int4*)&W3q[off];
                int sidx = (n0 + wrow + 16 * i) * SG + gn;
                pS1[i] = sc1[sidx]; pZ1[i] = zp1[sidx];
                pS3[i] = sc3[sidx]; pZ3[i] = zp3[sidx];
            }
        }
        __syncthreads();

        const unsigned short* sB = mat ? sW3 : sW1;
        #pragma unroll
        for (int kh = 0; kh < 2; ++kh) {
            const int kb = kh * 32 + q * 8;
            bf16x8 av[4], bv[4];
            #pragma unroll
            for (int im = 0; im < 4; ++im)
                av[im] = *(const bf16x8*)&sX[(mh + im * 16 + r) * LK + kb];
            #pragma unroll
            for (int j = 0; j < 4; ++j)
                bv[j] = *(const bf16x8*)&sB[(j * 16 + r) * LK + kb];
            #pragma unroll
            for (int im = 0; im < 4; ++im)
                #pragma unroll
                for (int j = 0; j < 4; ++j)
                    acc[im][j] = __builtin_amdgcn_mfma_f32_16x16x32_bf16(av[im], bv[j], acc[im][j], 0, 0, 0);
        }
        __syncthreads();
    }

    // ---- epilogue: exchange g3 via LDS, then silu(g1)*g3 ----
    if (mat == 1) {
        #pragma unroll
        for (int im = 0; im < 4; ++im)
            #pragma unroll
            for (int j = 0; j < 4; ++j)
                #pragma unroll
                for (int reg = 0; reg < 4; ++reg)
                    sEx[(mh + im * 16 + q * 4 + reg) * 65 + j * 16 + r] = acc[im][j][reg];
    }
    __syncthreads();
    if (mat == 0) {
        #pragma unroll
        for (int im = 0; im < 4; ++im)
            #pragma unroll
            for (int j = 0; j < 4; ++j)
                #pragma unroll
                for (int reg = 0; reg < 4; ++reg) {
                    int ml = mh + im * 16 + q * 4 + reg;
                    int nl = j * 16 + r;
                    float g1 = acc[im][j][reg];
                    float g3 = sEx[ml * 65 + nl];
                    float val = g1 / (1.f + __expf(-g1)) * g3;
                    G[(size_t)(m0 + ml) * F_DIM + n0 + nl] = f2bf(val);
                }
    }
}

// ---------------------------------------------------------------------------
// out += G @ W2^T (split-K, fp32 atomics). Tile M128 x N128 x K64, 4 waves
// x 64x64. Fully depth-1 pipelined like gate_up: G tile, W2, scales all
// register-prefetched. (256,2): ~185 regs, no spill.
// Grid: flat 1024 = 4(m) x 32(n) x 8(kseg), XCD-swizzled.
// ---------------------------------------------------------------------------
__global__ __launch_bounds__(256, 2)
void down_kernel(const unsigned short* __restrict__ G,
                 const int* __restrict__ W2q, const float* __restrict__ sc2,
                 const float* __restrict__ zp2,
                 float* __restrict__ Out)
{
    constexpr int LK = 72;
    __shared__ __align__(16) char smem[(128 + 128) * LK * 2];  // 36864 B
    unsigned short* sA = (unsigned short*)smem;
    unsigned short* sW = (unsigned short*)(smem + 128 * LK * 2);

    const int t = threadIdx.x, wave = t >> 6, lane = t & 63;
    const int r = lane & 15, q = lane >> 4;
    const int wm = (wave & 1) * 64, wn = (wave >> 1) * 64;

    const int b = blockIdx.x;
    const int xcd = b & 7, lb = b >> 3;          // lb in [0,128)
    const int m0 = (lb & 3) * 128;
    const int pair = xcd * 32 + (lb >> 2);       // [0,256)
    const int n0 = (pair >> 3) * 128;            // 32 n-tiles
    const int kbeg = (pair & 7) * (F_DIM / KSEG);
    const int kend = kbeg + (F_DIM / KSEG);
    const int SG = F_DIM / 64;

    const int arow = t >> 3, ach = (t & 7) * 8;
    const int wrow = t >> 4, wc = (t & 15) * 4;

    // ---- depth-1 pipeline registers ----
    int4  pA[4];
    int4  pW[8];
    float pS[8], pZ[8];

    #pragma unroll
    for (int i = 0; i < 4; ++i)
        pA[i] = *(const int4*)&G[(size_t)(m0 + arow + 32 * i) * F_DIM + kbeg + ach];
    #pragma unroll
    for (int i = 0; i < 8; ++i) {
        pW[i] = *(const int4*)&W2q[(size_t)(n0 + wrow + 16 * i) * F_DIM + kbeg + wc];
        int sidx = (n0 + wrow + 16 * i) * SG + (kbeg >> 6);
        pS[i] = sc2[sidx]; pZ[i] = zp2[sidx];
    }

    f32x4 acc[4][4];
    #pragma unroll
    for (int a = 0; a < 4; ++a)
        #pragma unroll
        for (int c = 0; c < 4; ++c) acc[a][c] = (f32x4){0.f, 0.f, 0.f, 0.f};

    for (int k0 = kbeg; k0 < kend; k0 += 64) {
        // ---- stage A tile (G bf16) from prefetch regs ----
        #pragma unroll
        for (int i = 0; i < 4; ++i)
            *(int4*)&sA[(arow + 32 * i) * LK + ach] = pA[i];
        // ---- dequant prefetched W2 -> LDS (scales from regs) ----
        #pragma unroll
        for (int i = 0; i < 8; ++i) {
            int row = wrow + 16 * i;
            float s = pS[i], nzs = -pZ[i] * s;
            int4 qv = pW[i];
            ushort4 o;
            o.x = f2bf(fmaf((float)qv.x, s, nzs)); o.y = f2bf(fmaf((float)qv.y, s, nzs));
            o.z = f2bf(fmaf((float)qv.z, s, nzs)); o.w = f2bf(fmaf((float)qv.w, s, nzs));
            *(ushort4*)&sW[row * LK + wc] = o;
        }
        // ---- issue ALL next-K-tile loads ----
        int kn = k0 + 64;
        if (kn < kend) {
            int gn = kn >> 6;
            #pragma unroll
            for (int i = 0; i < 4; ++i)
                pA[i] = *(const int4*)&G[(size_t)(m0 + arow + 32 * i) * F_DIM + kn + ach];
            #pragma unroll
            for (int i = 0; i < 8; ++i) {
                pW[i] = *(const int4*)&W2q[(size_t)(n0 + wrow + 16 * i) * F_DIM + kn + wc];
                int sidx = (n0 + wrow + 16 * i) * SG + gn;
                pS[i] = sc2[sidx]; pZ[i] = zp2[sidx];
            }
        }
        __syncthreads();

        #pragma unroll
        for (int kh = 0; kh < 2; ++kh) {
            const int kb = kh * 32 + q * 8;
            bf16x8 av[4], bv[4];
            #pragma unroll
            for (int im = 0; im < 4; ++im)
                av[im] = *(const bf16x8*)&sA[(wm + im * 16 + r) * LK + kb];
            #pragma unroll
            for (int j = 0; j < 4; ++j)
                bv[j] = *(const bf16x8*)&sW[(wn + j * 16 + r) * LK + kb];
            #pragma unroll
            for (int im = 0; im < 4; ++im)
                #pragma unroll
                for (int j = 0; j < 4; ++j)
                    acc[im][j] = __builtin_amdgcn_mfma_f32_16x16x32_bf16(av[im], bv[j], acc[im][j], 0, 0, 0);
        }
        __syncthreads();
    }

    #pragma unroll
    for (int im = 0; im < 4; ++im)
        #pragma unroll
        for (int j = 0; j < 4; ++j)
            #pragma unroll
            for (int reg = 0; reg < 4; ++reg) {
                int m = m0 + wm + im * 16 + q * 4 + reg;
                int h = n0 + wn + j * 16 + r;
                atomicAdd(&Out[(size_t)m * H_DIM + h], acc[im][j][reg]);
            }
}

extern "C" void kernel_launch(void* const* d_in, const int* in_sizes, int n_in,
                              void* d_out, int out_size, void* d_ws, size_t ws_size,
                              hipStream_t stream) {
    const float* X   = (const float*)d_in[0];
    const int*   W1q = (const int*)d_in[1];
    const float* s1  = (const float*)d_in[2];
    const float* z1  = (const float*)d_in[3];
    const int*   W3q = (const int*)d_in[4];
    const float* s3  = (const float*)d_in[5];
    const float* z3  = (const float*)d_in[6];
    const int*   W2q = (const int*)d_in[7];
    const float* s2  = (const float*)d_in[8];
    const float* z2  = (const float*)d_in[9];
    float* Out = (float*)d_out;

    unsigned short* Xb = (unsigned short*)d_ws;                       // 4 MB
    unsigned short* G  = (unsigned short*)((char*)d_ws + (4 << 20));  // 14.7 MB

    zero_out<<<2048, 256, 0, stream>>>((float4*)Out);
    cvt_x<<<2048, 256, 0, stream>>>(X, Xb);
    gate_up_kernel<<<896, 256, 0, stream>>>(Xb, W1q, s1, z1, W3q, s3, z3, G);
    down_kernel<<<1024, 256, 0, stream>>>(G, W2q, s2, z2, Out);
}

// Round 6
// 878.580 us; speedup vs baseline: 2.5776x; 1.3964x over previous
//
#include <hip/hip_runtime.h>
#include <hip/hip_bf16.h>

#define T_DIM 512
#define H_DIM 4096
#define F_DIM 14336
#define KSEG  8   // split-K segments for down GEMM (14336/8 = 1792 = 28 x 64)

typedef __attribute__((ext_vector_type(8))) short bf16x8;
typedef __attribute__((ext_vector_type(4))) float f32x4;

// 1-op f32->bf16 (v_cvt, RNE in HW). Confirmed R5: VALUBusy 25 -> 11.5.
// The old 4-op bit-trick RNE dominated the dequant phase.
__device__ __forceinline__ unsigned short f2bf(float f) {
    union { __hip_bfloat16 h; unsigned short u; } cv;
    cv.h = __float2bfloat16(f);
    return cv.u;
}

// Zero d_out (harness poisons with 0xAA; down_kernel accumulates via atomics).
__global__ __launch_bounds__(256) void zero_out(float4* __restrict__ out) {
    out[blockIdx.x * 256 + threadIdx.x] = make_float4(0.f, 0.f, 0.f, 0.f);
}

// X fp32 -> bf16 once.
__global__ __launch_bounds__(256) void cvt_x(const float* __restrict__ X,
                                             unsigned short* __restrict__ Xb) {
    int i = (blockIdx.x * 256 + threadIdx.x) * 4;
    float4 v = *(const float4*)&X[i];
    ushort4 o;
    o.x = f2bf(v.x); o.y = f2bf(v.y); o.z = f2bf(v.z); o.w = f2bf(v.w);
    *(ushort4*)&Xb[i] = o;
}

// ---------------------------------------------------------------------------
// G = silu(X@W1^T) * (X@W3^T) -> bf16 [T,F]
// Tile M128 x N64 x K64(=GROUP). 4 waves: wave&1 = m-half, wave>>1 = matrix.
// ONLY the weight streams (HBM-latency) are register-prefetched: 8 int4 =
// 32 VGPRs live across the barrier. X and scales are L2/L3-resident, loaded
// synchronously.
// REGISTER CLIFF (hard-won): this structure = 108 VGPR + 64 acc, NO spill,
// 347us. Every attempt to widen it spilled per-iteration scratch and was
// 1.5-4x SLOWER:
//   (256,4): VGPR squeezed to 64, 3 GB scratch, 1376us.
//   (256,3): VGPR 84, 650 MB scratch, 731us.
//   (256,2)+pX+pScale prefetch: VGPR 120 + 565 MB scratch WRITE, 527us.
// DO NOT raise min-waves bound; DO NOT extend register live ranges across
// the MFMA phase. Only change vs 347us baseline: cheap f2bf (R5-confirmed
// VALUBusy 25 -> 11.5).
// Grid: flat 896, XCD-swizzled (4 m-siblings concurrent per XCD).
// ---------------------------------------------------------------------------
__global__ __launch_bounds__(256, 2)
void gate_up_kernel(const unsigned short* __restrict__ Xb,
                    const int* __restrict__ W1q, const float* __restrict__ sc1,
                    const float* __restrict__ zp1,
                    const int* __restrict__ W3q, const float* __restrict__ sc3,
                    const float* __restrict__ zp3,
                    unsigned short* __restrict__ G)
{
    constexpr int LK = 72;  // 144 B row stride, 16B-aligned, +4 bank shift/row
    __shared__ __align__(16) char smem[(128 + 64 + 64) * LK * 2];  // 36864 B
    unsigned short* sX  = (unsigned short*)smem;
    unsigned short* sW1 = (unsigned short*)(smem + 128 * LK * 2);
    unsigned short* sW3 = (unsigned short*)(smem + 192 * LK * 2);
    float* sEx = (float*)smem;  // epilogue reuse: 128*65*4 = 33280 B

    const int t = threadIdx.x, wave = t >> 6, lane = t & 63;
    const int r = lane & 15, q = lane >> 4;
    const int mh  = (wave & 1) * 64;   // wave's m-offset in tile
    const int mat = wave >> 1;         // 0 -> W1, 1 -> W3

    const int b = blockIdx.x;
    const int xcd = b & 7, lb = b >> 3;         // lb in [0,112)
    const int m0 = (lb & 3) * 128;
    const int n0 = (xcd * 28 + (lb >> 2)) * 64; // n-tile in [0,224)
    const int SG = H_DIM / 64;

    const int xrow = t >> 3, xch = (t & 7) * 8;   // X: rows xrow+32i, 16B chunk
    const int wrow = t >> 4, wc = (t & 15) * 4;   // W: rows wrow+16i, 4 int32

    // weight-only prefetch (32 VGPRs live across barriers)
    int4 pW1[4], pW3[4];
    #pragma unroll
    for (int i = 0; i < 4; ++i) {
        size_t off = (size_t)(n0 + wrow + 16 * i) * H_DIM + wc;
        pW1[i] = *(const int4*)&W1q[off];
        pW3[i] = *(const int4*)&W3q[off];
    }

    f32x4 acc[4][4];
    #pragma unroll
    for (int a = 0; a < 4; ++a)
        #pragma unroll
        for (int c = 0; c < 4; ++c) acc[a][c] = (f32x4){0.f, 0.f, 0.f, 0.f};

    for (int k0 = 0; k0 < H_DIM; k0 += 64) {
        const int gidx = k0 >> 6;

        // ---- X tile: sync copy (L2/L3-resident, 4 MB total) ----
        #pragma unroll
        for (int i = 0; i < 4; ++i) {
            int4 xv = *(const int4*)&Xb[(size_t)(m0 + xrow + 32 * i) * H_DIM + k0 + xch];
            *(int4*)&sX[(xrow + 32 * i) * LK + xch] = xv;
        }
        // ---- dequant prefetched weights -> LDS (scales loaded sync, L2) ----
        #pragma unroll
        for (int i = 0; i < 4; ++i) {
            int row = wrow + 16 * i;
            int sidx = (n0 + row) * SG + gidx;
            float s = sc1[sidx], nzs = -zp1[sidx] * s;
            int4 qv = pW1[i];
            ushort4 o;
            o.x = f2bf(fmaf((float)qv.x, s, nzs)); o.y = f2bf(fmaf((float)qv.y, s, nzs));
            o.z = f2bf(fmaf((float)qv.z, s, nzs)); o.w = f2bf(fmaf((float)qv.w, s, nzs));
            *(ushort4*)&sW1[row * LK + wc] = o;
            s = sc3[sidx]; nzs = -zp3[sidx] * s;
            qv = pW3[i];
            o.x = f2bf(fmaf((float)qv.x, s, nzs)); o.y = f2bf(fmaf((float)qv.y, s, nzs));
            o.z = f2bf(fmaf((float)qv.z, s, nzs)); o.w = f2bf(fmaf((float)qv.w, s, nzs));
            *(ushort4*)&sW3[row * LK + wc] = o;
        }
        // ---- issue next K-tile's weight loads (stay in flight over MFMA) ----
        int kn = k0 + 64;
        if (kn < H_DIM) {
            #pragma unroll
            for (int i = 0; i < 4; ++i) {
                size_t off = (size_t)(n0 + wrow + 16 * i) * H_DIM + kn + wc;
                pW1[i] = *(const int4*)&W1q[off];
                pW3[i] = *(const int4*)&W3q[off];
            }
        }
        __syncthreads();

        const unsigned short* sB = mat ? sW3 : sW1;
        #pragma unroll
        for (int kh = 0; kh < 2; ++kh) {
            const int kb = kh * 32 + q * 8;
            bf16x8 av[4], bv[4];
            #pragma unroll
            for (int im = 0; im < 4; ++im)
                av[im] = *(const bf16x8*)&sX[(mh + im * 16 + r) * LK + kb];
            #pragma unroll
            for (int j = 0; j < 4; ++j)
                bv[j] = *(const bf16x8*)&sB[(j * 16 + r) * LK + kb];
            #pragma unroll
            for (int im = 0; im < 4; ++im)
                #pragma unroll
                for (int j = 0; j < 4; ++j)
                    acc[im][j] = __builtin_amdgcn_mfma_f32_16x16x32_bf16(av[im], bv[j], acc[im][j], 0, 0, 0);
        }
        __syncthreads();
    }

    // ---- epilogue: exchange g3 via LDS, then silu(g1)*g3 ----
    if (mat == 1) {
        #pragma unroll
        for (int im = 0; im < 4; ++im)
            #pragma unroll
            for (int j = 0; j < 4; ++j)
                #pragma unroll
                for (int reg = 0; reg < 4; ++reg)
                    sEx[(mh + im * 16 + q * 4 + reg) * 65 + j * 16 + r] = acc[im][j][reg];
    }
    __syncthreads();
    if (mat == 0) {
        #pragma unroll
        for (int im = 0; im < 4; ++im)
            #pragma unroll
            for (int j = 0; j < 4; ++j)
                #pragma unroll
                for (int reg = 0; reg < 4; ++reg) {
                    int ml = mh + im * 16 + q * 4 + reg;
                    int nl = j * 16 + r;
                    float g1 = acc[im][j][reg];
                    float g3 = sEx[ml * 65 + nl];
                    float val = g1 / (1.f + __expf(-g1)) * g3;
                    G[(size_t)(m0 + ml) * F_DIM + n0 + nl] = f2bf(val);
                }
    }
}

// ---------------------------------------------------------------------------
// out += G @ W2^T (split-K, fp32 atomics). Tile M128 x N128 x K64, 4 waves
// x 64x64. Weight-only register prefetch; G + scales loaded sync (L2/L3).
// Same register-cliff rules as gate_up. Only change vs baseline: cheap f2bf.
// Grid: flat 1024 = 4(m) x 32(n) x 8(kseg), XCD-swizzled.
// ---------------------------------------------------------------------------
__global__ __launch_bounds__(256, 2)
void down_kernel(const unsigned short* __restrict__ G,
                 const int* __restrict__ W2q, const float* __restrict__ sc2,
                 const float* __restrict__ zp2,
                 float* __restrict__ Out)
{
    constexpr int LK = 72;
    __shared__ __align__(16) char smem[(128 + 128) * LK * 2];  // 36864 B
    unsigned short* sA = (unsigned short*)smem;
    unsigned short* sW = (unsigned short*)(smem + 128 * LK * 2);

    const int t = threadIdx.x, wave = t >> 6, lane = t & 63;
    const int r = lane & 15, q = lane >> 4;
    const int wm = (wave & 1) * 64, wn = (wave >> 1) * 64;

    const int b = blockIdx.x;
    const int xcd = b & 7, lb = b >> 3;          // lb in [0,128)
    const int m0 = (lb & 3) * 128;
    const int pair = xcd * 32 + (lb >> 2);       // [0,256)
    const int n0 = (pair >> 3) * 128;            // 32 n-tiles
    const int kbeg = (pair & 7) * (F_DIM / KSEG);
    const int kend = kbeg + (F_DIM / KSEG);
    const int SG = F_DIM / 64;

    const int arow = t >> 3, ach = (t & 7) * 8;
    const int wrow = t >> 4, wc = (t & 15) * 4;

    // weight-only prefetch (32 VGPRs)
    int4 pW[8];
    #pragma unroll
    for (int i = 0; i < 8; ++i)
        pW[i] = *(const int4*)&W2q[(size_t)(n0 + wrow + 16 * i) * F_DIM + kbeg + wc];

    f32x4 acc[4][4];
    #pragma unroll
    for (int a = 0; a < 4; ++a)
        #pragma unroll
        for (int c = 0; c < 4; ++c) acc[a][c] = (f32x4){0.f, 0.f, 0.f, 0.f};

    for (int k0 = kbeg; k0 < kend; k0 += 64) {
        const int gidx = k0 >> 6;

        // ---- A tile (G bf16): sync copy (L3-resident, 14.7 MB) ----
        #pragma unroll
        for (int i = 0; i < 4; ++i) {
            int4 gv = *(const int4*)&G[(size_t)(m0 + arow + 32 * i) * F_DIM + k0 + ach];
            *(int4*)&sA[(arow + 32 * i) * LK + ach] = gv;
        }
        // ---- dequant prefetched W2 -> LDS ----
        #pragma unroll
        for (int i = 0; i < 8; ++i) {
            int row = wrow + 16 * i;
            int sidx = (n0 + row) * SG + gidx;
            float s = sc2[sidx], nzs = -zp2[sidx] * s;
            int4 qv = pW[i];
            ushort4 o;
            o.x = f2bf(fmaf((float)qv.x, s, nzs)); o.y = f2bf(fmaf((float)qv.y, s, nzs));
            o.z = f2bf(fmaf((float)qv.z, s, nzs)); o.w = f2bf(fmaf((float)qv.w, s, nzs));
            *(ushort4*)&sW[row * LK + wc] = o;
        }
        // ---- issue next K-tile weight loads ----
        int kn = k0 + 64;
        if (kn < kend) {
            #pragma unroll
            for (int i = 0; i < 8; ++i)
                pW[i] = *(const int4*)&W2q[(size_t)(n0 + wrow + 16 * i) * F_DIM + kn + wc];
        }
        __syncthreads();

        #pragma unroll
        for (int kh = 0; kh < 2; ++kh) {
            const int kb = kh * 32 + q * 8;
            bf16x8 av[4], bv[4];
            #pragma unroll
            for (int im = 0; im < 4; ++im)
                av[im] = *(const bf16x8*)&sA[(wm + im * 16 + r) * LK + kb];
            #pragma unroll
            for (int j = 0; j < 4; ++j)
                bv[j] = *(const bf16x8*)&sW[(wn + j * 16 + r) * LK + kb];
            #pragma unroll
            for (int im = 0; im < 4; ++im)
                #pragma unroll
                for (int j = 0; j < 4; ++j)
                    acc[im][j] = __builtin_amdgcn_mfma_f32_16x16x32_bf16(av[im], bv[j], acc[im][j], 0, 0, 0);
        }
        __syncthreads();
    }

    #pragma unroll
    for (int im = 0; im < 4; ++im)
        #pragma unroll
        for (int j = 0; j < 4; ++j)
            #pragma unroll
            for (int reg = 0; reg < 4; ++reg) {
                int m = m0 + wm + im * 16 + q * 4 + reg;
                int h = n0 + wn + j * 16 + r;
                atomicAdd(&Out[(size_t)m * H_DIM + h], acc[im][j][reg]);
            }
}

extern "C" void kernel_launch(void* const* d_in, const int* in_sizes, int n_in,
                              void* d_out, int out_size, void* d_ws, size_t ws_size,
                              hipStream_t stream) {
    const float* X   = (const float*)d_in[0];
    const int*   W1q = (const int*)d_in[1];
    const float* s1  = (const float*)d_in[2];
    const float* z1  = (const float*)d_in[3];
    const int*   W3q = (const int*)d_in[4];
    const float* s3  = (const float*)d_in[5];
    const float* z3  = (const float*)d_in[6];
    const int*   W2q = (const int*)d_in[7];
    const float* s2  = (const float*)d_in[8];
    const float* z2  = (const float*)d_in[9];
    float* Out = (float*)d_out;

    unsigned short* Xb = (unsigned short*)d_ws;                       // 4 MB
    unsigned short* G  = (unsigned short*)((char*)d_ws + (4 << 20));  // 14.7 MB

    zero_out<<<2048, 256, 0, stream>>>((float4*)Out);
    cvt_x<<<2048, 256, 0, stream>>>(X, Xb);
    gate_up_kernel<<<896, 256, 0, stream>>>(Xb, W1q, s1, z1, W3q, s3, z3, G);
    down_kernel<<<1024, 256, 0, stream>>>(G, W2q, s2, z2, Out);
}

// Round 7
// 873.263 us; speedup vs baseline: 2.5933x; 1.0061x over previous
//
#include <hip/hip_runtime.h>
#include <hip/hip_bf16.h>

#define T_DIM 512
#define H_DIM 4096
#define F_DIM 14336
#define KSEG  8   // split-K segments for down GEMM (14336/8 = 1792 = 28 x 64)

typedef __attribute__((ext_vector_type(8))) short bf16x8;
typedef __attribute__((ext_vector_type(4))) float f32x4;

// 1-op f32->bf16 (v_cvt, RNE in HW). Confirmed R5/R6: VALUBusy 25 -> 19.
__device__ __forceinline__ unsigned short f2bf(float f) {
    union { __hip_bfloat16 h; unsigned short u; } cv;
    cv.h = __float2bfloat16(f);
    return cv.u;
}

// dequant 4 int-quant values with (scale, zero) -> 4 bf16 -> 8B LDS store
__device__ __forceinline__ void dq16(int4 qv, float s, float z, unsigned short* dst) {
    float nzs = -z * s;
    ushort4 o;
    o.x = f2bf(fmaf((float)qv.x, s, nzs));
    o.y = f2bf(fmaf((float)qv.y, s, nzs));
    o.z = f2bf(fmaf((float)qv.z, s, nzs));
    o.w = f2bf(fmaf((float)qv.w, s, nzs));
    *(ushort4*)dst = o;
}

// Zero d_out (harness poisons with 0xAA; down_kernel accumulates via atomics).
__global__ __launch_bounds__(256) void zero_out(float4* __restrict__ out) {
    out[blockIdx.x * 256 + threadIdx.x] = make_float4(0.f, 0.f, 0.f, 0.f);
}

// X fp32 -> bf16 once.
__global__ __launch_bounds__(256) void cvt_x(const float* __restrict__ X,
                                             unsigned short* __restrict__ Xb) {
    int i = (blockIdx.x * 256 + threadIdx.x) * 4;
    float4 v = *(const float4*)&X[i];
    ushort4 o;
    o.x = f2bf(v.x); o.y = f2bf(v.y); o.z = f2bf(v.z); o.w = f2bf(v.w);
    *(ushort4*)&Xb[i] = o;
}

// ---------------------------------------------------------------------------
// G = silu(X@W1^T) * (X@W3^T) -> bf16 [T,F]
// Tile M128 x N64 x K64(=GROUP). 4 waves: wave&1 = m-half, wave>>1 = matrix.
// DOUBLE-BUFFERED LDS, ONE barrier per K-step:
//   MFMA(buf[it&1])  <- staged last iter, no entry wait
//   stage(buf[it^1]): X sync copy; dequant prefetched W regs; issue W(it+2)
//   __syncthreads()
// vs the old stage->barrier->MFMA->barrier (2 barriers + block-wide pre-MFMA
// staging wait). Waves stagger: early-finishing waves stage while others
// still MFMA. Register budget UNCHANGED (weight-only prefetch, 32 VGPR;
// X/scales sync) — the R5 lesson: source-forced reg live ranges across
// barriers spill (cliff at ~108 arch VGPR + 64 acc @ (256,2); (256,3)/(256,4)
// spill catastrophically. DO NOT raise min-waves; DO NOT widen reg prefetch).
// LDS 2 x 36864 = 73728 B -> still exactly 2 blocks/CU (147 KB < 160 KB).
// Grid: flat 896, XCD-swizzled (4 m-siblings concurrent per XCD).
// ---------------------------------------------------------------------------
__global__ __launch_bounds__(256, 2)
void gate_up_kernel(const unsigned short* __restrict__ Xb,
                    const int* __restrict__ W1q, const float* __restrict__ sc1,
                    const float* __restrict__ zp1,
                    const int* __restrict__ W3q, const float* __restrict__ sc3,
                    const float* __restrict__ zp3,
                    unsigned short* __restrict__ G)
{
    constexpr int LK = 72;  // 144 B row stride, 16B-aligned, +4 bank shift/row
    constexpr int BUFB = (128 + 64 + 64) * LK * 2;   // 36864 B per buffer
    __shared__ __align__(16) char smem[2 * BUFB];    // 73728 B
    float* sEx = (float*)smem;  // epilogue reuse of buf0: 128*65*4 = 33280 B

    const int t = threadIdx.x, wave = t >> 6, lane = t & 63;
    const int r = lane & 15, q = lane >> 4;
    const int mh  = (wave & 1) * 64;   // wave's m-offset in tile
    const int mat = wave >> 1;         // 0 -> W1, 1 -> W3

    const int b = blockIdx.x;
    const int xcd = b & 7, lb = b >> 3;         // lb in [0,112)
    const int m0 = (lb & 3) * 128;
    const int n0 = (xcd * 28 + (lb >> 2)) * 64; // n-tile in [0,224)
    const int SG = H_DIM / 64;

    const int xrow = t >> 3, xch = (t & 7) * 8;   // X: rows xrow+32i, 16B chunk
    const int wrow = t >> 4, wc = (t & 15) * 4;   // W: rows wrow+16i, 4 int32

    // weight-only prefetch (32 VGPRs live across barriers)
    int4 pW1[4], pW3[4];
    #pragma unroll
    for (int i = 0; i < 4; ++i) {
        size_t off = (size_t)(n0 + wrow + 16 * i) * H_DIM + wc;
        pW1[i] = *(const int4*)&W1q[off];
        pW3[i] = *(const int4*)&W3q[off];
    }

    // ---- prologue: stage tile 0 into buf0, then issue W(tile 1) ----
    {
        unsigned short* sX  = (unsigned short*)smem;
        unsigned short* sW1 = (unsigned short*)(smem + 128 * LK * 2);
        unsigned short* sW3 = (unsigned short*)(smem + 192 * LK * 2);
        #pragma unroll
        for (int i = 0; i < 4; ++i) {
            int4 xv = *(const int4*)&Xb[(size_t)(m0 + xrow + 32 * i) * H_DIM + xch];
            *(int4*)&sX[(xrow + 32 * i) * LK + xch] = xv;
        }
        #pragma unroll
        for (int i = 0; i < 4; ++i) {
            int row = wrow + 16 * i;
            int sidx = (n0 + row) * SG;   // gidx 0
            dq16(pW1[i], sc1[sidx], zp1[sidx], &sW1[row * LK + wc]);
            dq16(pW3[i], sc3[sidx], zp3[sidx], &sW3[row * LK + wc]);
        }
        #pragma unroll
        for (int i = 0; i < 4; ++i) {
            size_t off = (size_t)(n0 + wrow + 16 * i) * H_DIM + 64 + wc;
            pW1[i] = *(const int4*)&W1q[off];
            pW3[i] = *(const int4*)&W3q[off];
        }
    }
    __syncthreads();

    f32x4 acc[4][4];
    #pragma unroll
    for (int a = 0; a < 4; ++a)
        #pragma unroll
        for (int c = 0; c < 4; ++c) acc[a][c] = (f32x4){0.f, 0.f, 0.f, 0.f};

    constexpr int NIT = H_DIM / 64;   // 64
    #pragma unroll 2
    for (int it = 0; it < NIT; ++it) {
        const char* cb = smem + (it & 1) * BUFB;
        const unsigned short* sX = (const unsigned short*)cb;
        const unsigned short* sB =
            (const unsigned short*)(cb + (mat ? 192 : 128) * LK * 2);

        // ---- MFMA phase: tile `it` (staged last iter; no entry wait) ----
        #pragma unroll
        for (int kh = 0; kh < 2; ++kh) {
            const int kb = kh * 32 + q * 8;
            bf16x8 av[4], bv[4];
            #pragma unroll
            for (int im = 0; im < 4; ++im)
                av[im] = *(const bf16x8*)&sX[(mh + im * 16 + r) * LK + kb];
            #pragma unroll
            for (int j = 0; j < 4; ++j)
                bv[j] = *(const bf16x8*)&sB[(j * 16 + r) * LK + kb];
            #pragma unroll
            for (int im = 0; im < 4; ++im)
                #pragma unroll
                for (int j = 0; j < 4; ++j)
                    acc[im][j] = __builtin_amdgcn_mfma_f32_16x16x32_bf16(av[im], bv[j], acc[im][j], 0, 0, 0);
        }

        // ---- stage tile it+1 into the other buffer ----
        if (it < NIT - 1) {
            char* nb = smem + ((it + 1) & 1) * BUFB;
            unsigned short* nX  = (unsigned short*)nb;
            unsigned short* nW1 = (unsigned short*)(nb + 128 * LK * 2);
            unsigned short* nW3 = (unsigned short*)(nb + 192 * LK * 2);
            const int kn = (it + 1) * 64;
            #pragma unroll
            for (int i = 0; i < 4; ++i) {
                int4 xv = *(const int4*)&Xb[(size_t)(m0 + xrow + 32 * i) * H_DIM + kn + xch];
                *(int4*)&nX[(xrow + 32 * i) * LK + xch] = xv;
            }
            const int gidx = it + 1;
            #pragma unroll
            for (int i = 0; i < 4; ++i) {
                int row = wrow + 16 * i;
                int sidx = (n0 + row) * SG + gidx;
                dq16(pW1[i], sc1[sidx], zp1[sidx], &nW1[row * LK + wc]);
                dq16(pW3[i], sc3[sidx], zp3[sidx], &nW3[row * LK + wc]);
            }
            if (it < NIT - 2) {
                const int kf = (it + 2) * 64;
                #pragma unroll
                for (int i = 0; i < 4; ++i) {
                    size_t off = (size_t)(n0 + wrow + 16 * i) * H_DIM + kf + wc;
                    pW1[i] = *(const int4*)&W1q[off];
                    pW3[i] = *(const int4*)&W3q[off];
                }
            }
            __syncthreads();
        }
    }

    // ---- epilogue: exchange g3 via LDS (buf0 region; final MFMA read buf1,
    // disjoint), then silu(g1)*g3 ----
    if (mat == 1) {
        #pragma unroll
        for (int im = 0; im < 4; ++im)
            #pragma unroll
            for (int j = 0; j < 4; ++j)
                #pragma unroll
                for (int reg = 0; reg < 4; ++reg)
                    sEx[(mh + im * 16 + q * 4 + reg) * 65 + j * 16 + r] = acc[im][j][reg];
    }
    __syncthreads();
    if (mat == 0) {
        #pragma unroll
        for (int im = 0; im < 4; ++im)
            #pragma unroll
            for (int j = 0; j < 4; ++j)
                #pragma unroll
                for (int reg = 0; reg < 4; ++reg) {
                    int ml = mh + im * 16 + q * 4 + reg;
                    int nl = j * 16 + r;
                    float g1 = acc[im][j][reg];
                    float g3 = sEx[ml * 65 + nl];
                    float val = g1 / (1.f + __expf(-g1)) * g3;
                    G[(size_t)(m0 + ml) * F_DIM + n0 + nl] = f2bf(val);
                }
    }
}

// ---------------------------------------------------------------------------
// out += G @ W2^T (split-K, fp32 atomics). Tile M128 x N128 x K64, 4 waves
// x 64x64. Same double-buffer single-barrier restructure as gate_up.
// Weight-only register prefetch; G + scales loaded sync (L2/L3).
// Grid: flat 1024 = 4(m) x 32(n) x 8(kseg), XCD-swizzled.
// ---------------------------------------------------------------------------
__global__ __launch_bounds__(256, 2)
void down_kernel(const unsigned short* __restrict__ G,
                 const int* __restrict__ W2q, const float* __restrict__ sc2,
                 const float* __restrict__ zp2,
                 float* __restrict__ Out)
{
    constexpr int LK = 72;
    constexpr int BUFB = (128 + 128) * LK * 2;       // 36864 B per buffer
    __shared__ __align__(16) char smem[2 * BUFB];    // 73728 B

    const int t = threadIdx.x, wave = t >> 6, lane = t & 63;
    const int r = lane & 15, q = lane >> 4;
    const int wm = (wave & 1) * 64, wn = (wave >> 1) * 64;

    const int b = blockIdx.x;
    const int xcd = b & 7, lb = b >> 3;          // lb in [0,128)
    const int m0 = (lb & 3) * 128;
    const int pair = xcd * 32 + (lb >> 2);       // [0,256)
    const int n0 = (pair >> 3) * 128;            // 32 n-tiles
    const int kbeg = (pair & 7) * (F_DIM / KSEG);
    const int SG = F_DIM / 64;

    const int arow = t >> 3, ach = (t & 7) * 8;
    const int wrow = t >> 4, wc = (t & 15) * 4;

    // weight-only prefetch (32 VGPRs)
    int4 pW[8];
    #pragma unroll
    for (int i = 0; i < 8; ++i)
        pW[i] = *(const int4*)&W2q[(size_t)(n0 + wrow + 16 * i) * F_DIM + kbeg + wc];

    // ---- prologue: stage tile 0 into buf0, then issue W(tile 1) ----
    {
        unsigned short* sA = (unsigned short*)smem;
        unsigned short* sW = (unsigned short*)(smem + 128 * LK * 2);
        #pragma unroll
        for (int i = 0; i < 4; ++i) {
            int4 gv = *(const int4*)&G[(size_t)(m0 + arow + 32 * i) * F_DIM + kbeg + ach];
            *(int4*)&sA[(arow + 32 * i) * LK + ach] = gv;
        }
        const int gidx = kbeg >> 6;
        #pragma unroll
        for (int i = 0; i < 8; ++i) {
            int row = wrow + 16 * i;
            int sidx = (n0 + row) * SG + gidx;
            dq16(pW[i], sc2[sidx], zp2[sidx], &sW[row * LK + wc]);
        }
        #pragma unroll
        for (int i = 0; i < 8; ++i)
            pW[i] = *(const int4*)&W2q[(size_t)(n0 + wrow + 16 * i) * F_DIM + kbeg + 64 + wc];
    }
    __syncthreads();

    f32x4 acc[4][4];
    #pragma unroll
    for (int a = 0; a < 4; ++a)
        #pragma unroll
        for (int c = 0; c < 4; ++c) acc[a][c] = (f32x4){0.f, 0.f, 0.f, 0.f};

    constexpr int NIT = (F_DIM / KSEG) / 64;   // 28
    #pragma unroll 2
    for (int it = 0; it < NIT; ++it) {
        const char* cb = smem + (it & 1) * BUFB;
        const unsigned short* sA = (const unsigned short*)cb;
        const unsigned short* sW = (const unsigned short*)(cb + 128 * LK * 2);

        // ---- MFMA phase: tile `it` ----
        #pragma unroll
        for (int kh = 0; kh < 2; ++kh) {
            const int kb = kh * 32 + q * 8;
            bf16x8 av[4], bv[4];
            #pragma unroll
            for (int im = 0; im < 4; ++im)
                av[im] = *(const bf16x8*)&sA[(wm + im * 16 + r) * LK + kb];
            #pragma unroll
            for (int j = 0; j < 4; ++j)
                bv[j] = *(const bf16x8*)&sW[(wn + j * 16 + r) * LK + kb];
            #pragma unroll
            for (int im = 0; im < 4; ++im)
                #pragma unroll
                for (int j = 0; j < 4; ++j)
                    acc[im][j] = __builtin_amdgcn_mfma_f32_16x16x32_bf16(av[im], bv[j], acc[im][j], 0, 0, 0);
        }

        // ---- stage tile it+1 ----
        if (it < NIT - 1) {
            char* nb = smem + ((it + 1) & 1) * BUFB;
            unsigned short* nA = (unsigned short*)nb;
            unsigned short* nW = (unsigned short*)(nb + 128 * LK * 2);
            const int kn = kbeg + (it + 1) * 64;
            #pragma unroll
            for (int i = 0; i < 4; ++i) {
                int4 gv = *(const int4*)&G[(size_t)(m0 + arow + 32 * i) * F_DIM + kn + ach];
                *(int4*)&nA[(arow + 32 * i) * LK + ach] = gv;
            }
            const int gidx = kn >> 6;
            #pragma unroll
            for (int i = 0; i < 8; ++i) {
                int row = wrow + 16 * i;
                int sidx = (n0 + row) * SG + gidx;
                dq16(pW[i], sc2[sidx], zp2[sidx], &nW[row * LK + wc]);
            }
            if (it < NIT - 2) {
                const int kf = kbeg + (it + 2) * 64;
                #pragma unroll
                for (int i = 0; i < 8; ++i)
                    pW[i] = *(const int4*)&W2q[(size_t)(n0 + wrow + 16 * i) * F_DIM + kf + wc];
            }
            __syncthreads();
        }
    }

    #pragma unroll
    for (int im = 0; im < 4; ++im)
        #pragma unroll
        for (int j = 0; j < 4; ++j)
            #pragma unroll
            for (int reg = 0; reg < 4; ++reg) {
                int m = m0 + wm + im * 16 + q * 4 + reg;
                int h = n0 + wn + j * 16 + r;
                atomicAdd(&Out[(size_t)m * H_DIM + h], acc[im][j][reg]);
            }
}

extern "C" void kernel_launch(void* const* d_in, const int* in_sizes, int n_in,
                              void* d_out, int out_size, void* d_ws, size_t ws_size,
                              hipStream_t stream) {
    const float* X   = (const float*)d_in[0];
    const int*   W1q = (const int*)d_in[1];
    const float* s1  = (const float*)d_in[2];
    const float* z1  = (const float*)d_in[3];
    const int*   W3q = (const int*)d_in[4];
    const float* s3  = (const float*)d_in[5];
    const float* z3  = (const float*)d_in[6];
    const int*   W2q = (const int*)d_in[7];
    const float* s2  = (const float*)d_in[8];
    const float* z2  = (const float*)d_in[9];
    float* Out = (float*)d_out;

    unsigned short* Xb = (unsigned short*)d_ws;                       // 4 MB
    unsigned short* G  = (unsigned short*)((char*)d_ws + (4 << 20));  // 14.7 MB

    zero_out<<<2048, 256, 0, stream>>>((float4*)Out);
    cvt_x<<<2048, 256, 0, stream>>>(X, Xb);
    gate_up_kernel<<<896, 256, 0, stream>>>(Xb, W1q, s1, z1, W3q, s3, z3, G);
    down_kernel<<<1024, 256, 0, stream>>>(G, W2q, s2, z2, Out);
}